// Round 1
// baseline (1174.576 us; speedup 1.0000x reference)
//
#include <hip/hip_runtime.h>
#include <math.h>

#define HIDDEN 1024
#define HEAD_DIM 64
#define NEXP 16
#define NTOK 8192          // B*T
#define SEQ 2048
#define NB 4

// ---------------- workspace layout ----------------
// off 0      : prep      32 f32  (invnorm[16], sig_gates[16])
// off 256    : counts    16 i32
// off 512    : tok_list  16*8192 i32   (512 KB)
// off 524800 : wgt_list  16*8192 f32   (512 KB)
// off 1049088: qb   8192*64 f32 (2 MB)
// off 3146240: kb   2 MB
// off 5243392: vb   2 MB
// off 7340544: attn 2 MB
#define OFF_PREP   0
#define OFF_CNT    256
#define OFF_TOK    512
#define OFF_WGT    (512 + 524288)
#define OFF_Q      (OFF_WGT + 524288)
#define OFF_K      (OFF_Q + 2097152)
#define OFF_V      (OFF_K + 2097152)
#define OFF_ATTN   (OFF_V + 2097152)

// ---------------- prep: sim column inv-norms + sigmoid(gates) ----------------
__global__ __launch_bounds__(256) void prep_kernel(const float* __restrict__ sim,
                                                   const float* __restrict__ gates,
                                                   float* __restrict__ prep) {
    int tid = threadIdx.x;
    int e = tid & 15, part = tid >> 4;   // 16 parts per column
    float ss = 0.f;
    for (int c = part; c < HIDDEN; c += 16) {
        float v = sim[c * NEXP + e];
        ss += v * v;
    }
    __shared__ float red[16][17];
    red[part][e] = ss;
    __syncthreads();
    if (tid < 16) {
        float s = 0.f;
        #pragma unroll
        for (int p = 0; p < 16; ++p) s += red[p][tid];
        prep[tid] = 1.f / fmaxf(sqrtf(s), 1e-12f);
        prep[16 + tid] = 1.f / (1.f + expf(-gates[tid]));
    }
}

// ---------------- gating: per-token rw + expert-major dispatch lists ----------------
__global__ __launch_bounds__(256) void gating_kernel(const float* __restrict__ h,
                                                     const float* __restrict__ sim,
                                                     const float* __restrict__ prep,
                                                     int* __restrict__ counts,
                                                     int* __restrict__ tok_list,
                                                     float* __restrict__ wgt_list) {
    int t = blockIdx.x;
    int tid = threadIdx.x;
    const float* hrow = h + (size_t)t * HIDDEN;
    float dot[16];
    #pragma unroll
    for (int e = 0; e < 16; ++e) dot[e] = 0.f;
    float ss = 0.f;
    for (int c = tid; c < HIDDEN; c += 256) {
        float hv = hrow[c];
        ss += hv * hv;
        const float4* s4 = (const float4*)(sim + c * NEXP);
        float4 a = s4[0], b = s4[1], cc = s4[2], d = s4[3];
        dot[0]  += hv * a.x;  dot[1]  += hv * a.y;  dot[2]  += hv * a.z;  dot[3]  += hv * a.w;
        dot[4]  += hv * b.x;  dot[5]  += hv * b.y;  dot[6]  += hv * b.z;  dot[7]  += hv * b.w;
        dot[8]  += hv * cc.x; dot[9]  += hv * cc.y; dot[10] += hv * cc.z; dot[11] += hv * cc.w;
        dot[12] += hv * d.x;  dot[13] += hv * d.y;  dot[14] += hv * d.z;  dot[15] += hv * d.w;
    }
    int lane = tid & 63, wv = tid >> 6;
    #pragma unroll
    for (int off = 32; off > 0; off >>= 1) {
        ss += __shfl_down(ss, off, 64);
        #pragma unroll
        for (int e = 0; e < 16; ++e) dot[e] += __shfl_down(dot[e], off, 64);
    }
    __shared__ float red[4][17];
    if (lane == 0) {
        red[wv][16] = ss;
        #pragma unroll
        for (int e = 0; e < 16; ++e) red[wv][e] = dot[e];
    }
    __syncthreads();
    if (tid == 0) {
        float tss = 0.f;
        float td[16];
        #pragma unroll
        for (int e = 0; e < 16; ++e) td[e] = 0.f;
        for (int w = 0; w < 4; ++w) {
            tss += red[w][16];
            #pragma unroll
            for (int e = 0; e < 16; ++e) td[e] += red[w][e];
        }
        float invh = 1.f / fmaxf(sqrtf(tss), 1e-12f);
        float logits[16], gated[16];
        bool mask[16];
        int nact = 0;
        #pragma unroll
        for (int e = 0; e < 16; ++e) {
            logits[e] = td[e] * invh * prep[e] - prep[16 + e];
            gated[e] = fmaxf(logits[e], 0.f);
            mask[e] = logits[e] > 0.f;
            if (mask[e]) nact++;
        }
        if (nact == 0) {
            // top-2 fallback by logits (stable: lower index wins ties)
            int i1 = 0; float v1 = logits[0];
            for (int e = 1; e < 16; ++e) if (logits[e] > v1) { v1 = logits[e]; i1 = e; }
            int i2 = -1; float v2 = -INFINITY;
            for (int e = 0; e < 16; ++e) if (e != i1 && logits[e] > v2) { v2 = logits[e]; i2 = e; }
            mask[i1] = true; mask[i2] = true;
        }
        // softmax over masked gated values
        float m = -INFINITY;
        #pragma unroll
        for (int e = 0; e < 16; ++e) if (mask[e]) m = fmaxf(m, gated[e]);
        float sum = 0.f;
        float p[16];
        #pragma unroll
        for (int e = 0; e < 16; ++e) {
            p[e] = mask[e] ? expf(gated[e] - m) : 0.f;
            sum += p[e];
        }
        float inv = 1.f / sum;
        for (int e = 0; e < 16; ++e) {
            if (mask[e]) {
                float w = p[e] * inv;
                int pos = atomicAdd(&counts[e], 1);
                tok_list[e * NTOK + pos] = t;
                wgt_list[e * NTOK + pos] = w;
            }
        }
    }
}

// ---------------- per-expert gathered GEMM: q/k/v = w * (h @ W[e]) ----------------
// grid.x = 16 experts * 128 chunks, grid.y = 3 (q,k,v); block 256
__global__ __launch_bounds__(256) void expert_qkv_kernel(const float* __restrict__ h,
                                                         const float* __restrict__ qw,
                                                         const float* __restrict__ kw,
                                                         const float* __restrict__ vw,
                                                         const int* __restrict__ counts,
                                                         const int* __restrict__ tok_list,
                                                         const float* __restrict__ wgt_list,
                                                         float* __restrict__ qo,
                                                         float* __restrict__ ko,
                                                         float* __restrict__ vo) {
    int e = blockIdx.x >> 7, chunk = blockIdx.x & 127;
    int cnt = counts[e];
    int base = chunk * 64;
    if (base >= cnt) return;
    int tensor = blockIdx.y;
    const float* W = (tensor == 0 ? qw : tensor == 1 ? kw : vw) + (size_t)e * HIDDEN * HEAD_DIM;
    float* out = tensor == 0 ? qo : tensor == 1 ? ko : vo;

    __shared__ int s_tok[64];
    __shared__ float s_wt[64];
    __shared__ float h_sT[32][68];   // [k][token]
    __shared__ float w_s[32][68];    // [k][d]
    int tid = threadIdx.x;
    if (tid < 64) {
        int idx = base + tid;
        s_tok[tid] = idx < cnt ? tok_list[e * NTOK + idx] : -1;
        s_wt[tid] = idx < cnt ? wgt_list[e * NTOK + idx] : 0.f;
    }
    __syncthreads();
    int tr = tid >> 4, tc = tid & 15;
    float acc[4][4];
    #pragma unroll
    for (int i = 0; i < 4; ++i)
        #pragma unroll
        for (int j = 0; j < 4; ++j) acc[i][j] = 0.f;

    int tokl = tid >> 2, cg = tid & 3;
    int tg_stage = s_tok[tokl];
    int kk = tid >> 3, dg = tid & 7;

    for (int kt = 0; kt < 32; ++kt) {
        __syncthreads();
        // stage h (transposed) — 64 tokens x 32 channels
        #pragma unroll
        for (int r = 0; r < 2; ++r) {
            int c = cg * 8 + r * 4;
            float4 hv = make_float4(0.f, 0.f, 0.f, 0.f);
            if (tg_stage >= 0) hv = *(const float4*)&h[(size_t)tg_stage * HIDDEN + kt * 32 + c];
            h_sT[c + 0][tokl] = hv.x;
            h_sT[c + 1][tokl] = hv.y;
            h_sT[c + 2][tokl] = hv.z;
            h_sT[c + 3][tokl] = hv.w;
        }
        // stage W — 32 channels x 64 dims
        {
            const float* wr = W + (size_t)(kt * 32 + kk) * HEAD_DIM + dg * 8;
            float4 w0 = *(const float4*)wr;
            float4 w1 = *(const float4*)(wr + 4);
            *(float4*)&w_s[kk][dg * 8] = w0;
            *(float4*)&w_s[kk][dg * 8 + 4] = w1;
        }
        __syncthreads();
        #pragma unroll
        for (int k2 = 0; k2 < 32; ++k2) {
            float4 a4 = *(float4*)&h_sT[k2][tr * 4];
            float4 b4 = *(float4*)&w_s[k2][tc * 4];
            float av[4] = {a4.x, a4.y, a4.z, a4.w};
            float bv[4] = {b4.x, b4.y, b4.z, b4.w};
            #pragma unroll
            for (int i = 0; i < 4; ++i)
                #pragma unroll
                for (int j = 0; j < 4; ++j) acc[i][j] += av[i] * bv[j];
        }
    }
    #pragma unroll
    for (int i = 0; i < 4; ++i) {
        int r = tr * 4 + i;
        int tg = s_tok[r];
        if (tg >= 0) {
            float w = s_wt[r];
            #pragma unroll
            for (int j = 0; j < 4; ++j)
                atomicAdd(&out[(size_t)tg * HEAD_DIM + tc * 4 + j], w * acc[i][j]);
        }
    }
}

// ---------------- flash causal attention, fp32 ----------------
// grid (64 qtiles, 4 batches); block 256; qtile=32, ktile=64
__global__ __launch_bounds__(256) void attn_kernel(const float* __restrict__ q,
                                                   const float* __restrict__ k,
                                                   const float* __restrict__ v,
                                                   float* __restrict__ o) {
    int b = blockIdx.y;
    int q0 = blockIdx.x * 32;
    int tid = threadIdx.x;
    int row = tid & 31, grp = tid >> 5;   // 8 groups
    int qg = q0 + row;

    __shared__ float k_s[64][68];
    __shared__ float v_s[64][68];
    __shared__ float p_s[32][68];
    __shared__ float red[8][32];

    // q row in registers
    float4 qv[16];
    const float* qrow = q + ((size_t)(b * SEQ + qg)) * HEAD_DIM;
    #pragma unroll
    for (int i = 0; i < 16; ++i) qv[i] = *(const float4*)(qrow + i * 4);

    float acc[8];
    #pragma unroll
    for (int i = 0; i < 8; ++i) acc[i] = 0.f;
    float m = -INFINITY, l = 0.f;

    int nkt = (q0 + 32 + 63) >> 6;
    int kr = tid >> 2, dg4 = (tid & 3) * 16;
    int k0 = grp * 8;

    for (int kt = 0; kt < nkt; ++kt) {
        __syncthreads();   // (A) prior-tile reads done
        {
            const float* krg = k + ((size_t)(b * SEQ + kt * 64 + kr)) * HEAD_DIM + dg4;
            const float* vrg = v + ((size_t)(b * SEQ + kt * 64 + kr)) * HEAD_DIM + dg4;
            #pragma unroll
            for (int r = 0; r < 4; ++r) {
                *(float4*)&k_s[kr][dg4 + r * 4] = *(const float4*)(krg + r * 4);
                *(float4*)&v_s[kr][dg4 + r * 4] = *(const float4*)(vrg + r * 4);
            }
        }
        __syncthreads();   // (B)
        float s[8];
        #pragma unroll
        for (int i = 0; i < 8; ++i) s[i] = 0.f;
        #pragma unroll
        for (int d0 = 0; d0 < 16; ++d0) {
            float4 a = qv[d0];
            #pragma unroll
            for (int i = 0; i < 8; ++i) {
                float4 kk4 = *(float4*)&k_s[k0 + i][d0 * 4];
                s[i] += a.x * kk4.x + a.y * kk4.y + a.z * kk4.z + a.w * kk4.w;
            }
        }
        float pm = -INFINITY;
        #pragma unroll
        for (int i = 0; i < 8; ++i) {
            int kg = kt * 64 + k0 + i;
            s[i] = (kg <= qg) ? s[i] * 0.125f : -INFINITY;
            pm = fmaxf(pm, s[i]);
        }
        red[grp][row] = pm;
        __syncthreads();   // (C)
        float tm = -INFINITY;
        #pragma unroll
        for (int g = 0; g < 8; ++g) tm = fmaxf(tm, red[g][row]);
        float mnew = fmaxf(m, tm);
        float corr = __expf(m - mnew);
        float p[8];
        float psum = 0.f;
        #pragma unroll
        for (int i = 0; i < 8; ++i) {
            p[i] = __expf(s[i] - mnew);
            psum += p[i];
        }
        __syncthreads();   // (D) red reads done
        red[grp][row] = psum;
        __syncthreads();   // (E)
        float tsum = 0.f;
        #pragma unroll
        for (int g = 0; g < 8; ++g) tsum += red[g][row];
        l = l * corr + tsum;
        m = mnew;
        #pragma unroll
        for (int i = 0; i < 8; ++i) p_s[row][k0 + i] = p[i];
        #pragma unroll
        for (int d = 0; d < 8; ++d) acc[d] *= corr;
        __syncthreads();   // (F) p_s visible
        #pragma unroll 8
        for (int k2 = 0; k2 < 64; ++k2) {
            float pv = p_s[row][k2];
            float4 v0 = *(float4*)&v_s[k2][grp * 8];
            float4 v1 = *(float4*)&v_s[k2][grp * 8 + 4];
            acc[0] += pv * v0.x; acc[1] += pv * v0.y; acc[2] += pv * v0.z; acc[3] += pv * v0.w;
            acc[4] += pv * v1.x; acc[5] += pv * v1.y; acc[6] += pv * v1.z; acc[7] += pv * v1.w;
        }
    }
    float invl = 1.f / l;
    float* orow = o + ((size_t)(b * SEQ + qg)) * HEAD_DIM + grp * 8;
    float4 o0 = make_float4(acc[0] * invl, acc[1] * invl, acc[2] * invl, acc[3] * invl);
    float4 o1 = make_float4(acc[4] * invl, acc[5] * invl, acc[6] * invl, acc[7] * invl);
    *(float4*)orow = o0;
    *(float4*)(orow + 4) = o1;
}

// ---------------- per-expert output projection: out += (w*attn) @ Wo[e] ----------------
// grid.x = 16 experts * 128 chunks, grid.y = 8 column chunks of 128; block 256
__global__ __launch_bounds__(256) void expert_out_kernel(const float* __restrict__ attn,
                                                         const float* __restrict__ ow,
                                                         const int* __restrict__ counts,
                                                         const int* __restrict__ tok_list,
                                                         const float* __restrict__ wgt_list,
                                                         float* __restrict__ out) {
    int e = blockIdx.x >> 7, chunk = blockIdx.x & 127;
    int cnt = counts[e];
    int base = chunk * 64;
    if (base >= cnt) return;
    int cbase = blockIdx.y * 128;

    __shared__ int s_tok[64];
    __shared__ float s_wt[64];
    __shared__ float x_sT[64][68];    // [d][token], weight folded in
    __shared__ float w_s[64][132];    // [d][c]
    int tid = threadIdx.x;
    if (tid < 64) {
        int idx = base + tid;
        s_tok[tid] = idx < cnt ? tok_list[e * NTOK + idx] : -1;
        s_wt[tid] = idx < cnt ? wgt_list[e * NTOK + idx] : 0.f;
    }
    __syncthreads();
    // stage X = w * attn rows (transposed)
    {
        int tokl = tid >> 2, dg = tid & 3;
        int tg = s_tok[tokl];
        float w = s_wt[tokl];
        #pragma unroll
        for (int r = 0; r < 4; ++r) {
            int d = dg * 16 + r * 4;
            float4 av = make_float4(0.f, 0.f, 0.f, 0.f);
            if (tg >= 0) av = *(const float4*)&attn[(size_t)tg * HEAD_DIM + d];
            x_sT[d + 0][tokl] = w * av.x;
            x_sT[d + 1][tokl] = w * av.y;
            x_sT[d + 2][tokl] = w * av.z;
            x_sT[d + 3][tokl] = w * av.w;
        }
    }
    // stage Wo slice: 64 x 128
    {
        int kk = tid >> 2, qd = tid & 3;
        const float* wr = ow + (size_t)e * HEAD_DIM * HIDDEN + (size_t)kk * HIDDEN + cbase;
        #pragma unroll
        for (int r = 0; r < 8; ++r) {
            int c = qd * 32 + r * 4;
            *(float4*)&w_s[kk][c] = *(const float4*)(wr + c);
        }
    }
    __syncthreads();
    int tr = tid >> 4, tc = tid & 15;
    float acc[4][8];
    #pragma unroll
    for (int i = 0; i < 4; ++i)
        #pragma unroll
        for (int j = 0; j < 8; ++j) acc[i][j] = 0.f;
    #pragma unroll 4
    for (int kk = 0; kk < 64; ++kk) {
        float4 a4 = *(float4*)&x_sT[kk][tr * 4];
        float4 b0 = *(float4*)&w_s[kk][tc * 8];
        float4 b1 = *(float4*)&w_s[kk][tc * 8 + 4];
        float av[4] = {a4.x, a4.y, a4.z, a4.w};
        float bv[8] = {b0.x, b0.y, b0.z, b0.w, b1.x, b1.y, b1.z, b1.w};
        #pragma unroll
        for (int i = 0; i < 4; ++i)
            #pragma unroll
            for (int j = 0; j < 8; ++j) acc[i][j] += av[i] * bv[j];
    }
    #pragma unroll
    for (int i = 0; i < 4; ++i) {
        int r = tr * 4 + i;
        int tg = s_tok[r];
        if (tg >= 0) {
            #pragma unroll
            for (int j = 0; j < 8; ++j)
                atomicAdd(&out[(size_t)tg * HIDDEN + cbase + tc * 8 + j], acc[i][j]);
        }
    }
}

extern "C" void kernel_launch(void* const* d_in, const int* in_sizes, int n_in,
                              void* d_out, int out_size, void* d_ws, size_t ws_size,
                              hipStream_t stream) {
    const float* h     = (const float*)d_in[0];
    const float* sim   = (const float*)d_in[1];
    const float* gates = (const float*)d_in[2];
    const float* qw    = (const float*)d_in[3];
    const float* kw    = (const float*)d_in[4];
    const float* vw    = (const float*)d_in[5];
    const float* ow    = (const float*)d_in[6];
    float* out = (float*)d_out;

    char* w = (char*)d_ws;
    float* prep     = (float*)(w + OFF_PREP);
    int*   counts   = (int*)(w + OFF_CNT);
    int*   tok_list = (int*)(w + OFF_TOK);
    float* wgt_list = (float*)(w + OFF_WGT);
    float* qb       = (float*)(w + OFF_Q);
    float* kb       = (float*)(w + OFF_K);
    float* vb       = (float*)(w + OFF_V);
    float* attnb    = (float*)(w + OFF_ATTN);

    hipMemsetAsync(counts, 0, 64, stream);
    hipMemsetAsync(qb, 0, 3 * 2097152, stream);           // q,k,v contiguous
    hipMemsetAsync(out, 0, (size_t)out_size * 4, stream);

    prep_kernel<<<1, 256, 0, stream>>>(sim, gates, prep);
    gating_kernel<<<NTOK, 256, 0, stream>>>(h, sim, prep, counts, tok_list, wgt_list);
    expert_qkv_kernel<<<dim3(16 * 128, 3), 256, 0, stream>>>(h, qw, kw, vw, counts, tok_list,
                                                             wgt_list, qb, kb, vb);
    attn_kernel<<<dim3(64, 4), 256, 0, stream>>>(qb, kb, vb, attnb);
    expert_out_kernel<<<dim3(16 * 128, 8), 256, 0, stream>>>(attnb, ow, counts, tok_list,
                                                             wgt_list, out);
}

// Round 2
// 787.064 us; speedup vs baseline: 1.4924x; 1.4924x over previous
//
#include <hip/hip_runtime.h>
#include <math.h>

#define HIDDEN 1024
#define HEAD_DIM 64
#define NEXP 16
#define NTOK 8192          // B*T
#define SEQ 2048
#define NB 4

// ---------------- workspace layout ----------------
#define OFF_PREP   0
#define OFF_CNT    256
#define OFF_TOK    512
#define OFF_WGT    (512 + 524288)
#define OFF_RW     (OFF_WGT + 524288)
#define OFF_Q      (OFF_RW + 524288)
#define OFF_K      (OFF_Q + 2097152)
#define OFF_V      (OFF_K + 2097152)
#define OFF_ATTN   (OFF_V + 2097152)

// ---------------- prep: sim column inv-norms + sigmoid(gates) ----------------
__global__ __launch_bounds__(256) void prep_kernel(const float* __restrict__ sim,
                                                   const float* __restrict__ gates,
                                                   float* __restrict__ prep) {
    int tid = threadIdx.x;
    int e = tid & 15, part = tid >> 4;   // 16 parts per column
    float ss = 0.f;
    for (int c = part; c < HIDDEN; c += 16) {
        float v = sim[c * NEXP + e];
        ss += v * v;
    }
    __shared__ float red[16][17];
    red[part][e] = ss;
    __syncthreads();
    if (tid < 16) {
        float s = 0.f;
        #pragma unroll
        for (int p = 0; p < 16; ++p) s += red[p][tid];
        prep[tid] = 1.f / fmaxf(sqrtf(s), 1e-12f);
        prep[16 + tid] = 1.f / (1.f + expf(-gates[tid]));
    }
}

// ---------------- gating: per-token rw + expert-major dispatch lists + dense rw ----------------
__global__ __launch_bounds__(256) void gating_kernel(const float* __restrict__ h,
                                                     const float* __restrict__ sim,
                                                     const float* __restrict__ prep,
                                                     int* __restrict__ counts,
                                                     int* __restrict__ tok_list,
                                                     float* __restrict__ wgt_list,
                                                     float* __restrict__ rw_dense) {
    int t = blockIdx.x;
    int tid = threadIdx.x;
    const float* hrow = h + (size_t)t * HIDDEN;
    float dot[16];
    #pragma unroll
    for (int e = 0; e < 16; ++e) dot[e] = 0.f;
    float ss = 0.f;
    for (int c = tid; c < HIDDEN; c += 256) {
        float hv = hrow[c];
        ss += hv * hv;
        const float4* s4 = (const float4*)(sim + c * NEXP);
        float4 a = s4[0], b = s4[1], cc = s4[2], d = s4[3];
        dot[0]  += hv * a.x;  dot[1]  += hv * a.y;  dot[2]  += hv * a.z;  dot[3]  += hv * a.w;
        dot[4]  += hv * b.x;  dot[5]  += hv * b.y;  dot[6]  += hv * b.z;  dot[7]  += hv * b.w;
        dot[8]  += hv * cc.x; dot[9]  += hv * cc.y; dot[10] += hv * cc.z; dot[11] += hv * cc.w;
        dot[12] += hv * d.x;  dot[13] += hv * d.y;  dot[14] += hv * d.z;  dot[15] += hv * d.w;
    }
    int lane = tid & 63, wv = tid >> 6;
    #pragma unroll
    for (int off = 32; off > 0; off >>= 1) {
        ss += __shfl_down(ss, off, 64);
        #pragma unroll
        for (int e = 0; e < 16; ++e) dot[e] += __shfl_down(dot[e], off, 64);
    }
    __shared__ float red[4][17];
    if (lane == 0) {
        red[wv][16] = ss;
        #pragma unroll
        for (int e = 0; e < 16; ++e) red[wv][e] = dot[e];
    }
    __syncthreads();
    if (tid == 0) {
        float tss = 0.f;
        float td[16];
        #pragma unroll
        for (int e = 0; e < 16; ++e) td[e] = 0.f;
        for (int w = 0; w < 4; ++w) {
            tss += red[w][16];
            #pragma unroll
            for (int e = 0; e < 16; ++e) td[e] += red[w][e];
        }
        float invh = 1.f / fmaxf(sqrtf(tss), 1e-12f);
        float logits[16], gated[16];
        bool mask[16];
        int nact = 0;
        #pragma unroll
        for (int e = 0; e < 16; ++e) {
            logits[e] = td[e] * invh * prep[e] - prep[16 + e];
            gated[e] = fmaxf(logits[e], 0.f);
            mask[e] = logits[e] > 0.f;
            if (mask[e]) nact++;
        }
        if (nact == 0) {
            int i1 = 0; float v1 = logits[0];
            for (int e = 1; e < 16; ++e) if (logits[e] > v1) { v1 = logits[e]; i1 = e; }
            int i2 = -1; float v2 = -INFINITY;
            for (int e = 0; e < 16; ++e) if (e != i1 && logits[e] > v2) { v2 = logits[e]; i2 = e; }
            mask[i1] = true; mask[i2] = true;
        }
        float m = -INFINITY;
        #pragma unroll
        for (int e = 0; e < 16; ++e) if (mask[e]) m = fmaxf(m, gated[e]);
        float sum = 0.f;
        float p[16];
        #pragma unroll
        for (int e = 0; e < 16; ++e) {
            p[e] = mask[e] ? expf(gated[e] - m) : 0.f;
            sum += p[e];
        }
        float inv = 1.f / sum;
        for (int e = 0; e < 16; ++e) {
            if (mask[e]) {
                float w = p[e] * inv;
                rw_dense[(size_t)t * 16 + e] = w;
                int pos = atomicAdd(&counts[e], 1);
                tok_list[e * NTOK + pos] = t;
                wgt_list[e * NTOK + pos] = w;
            } else {
                rw_dense[(size_t)t * 16 + e] = 0.f;
            }
        }
    }
}

// ---------------- per-expert gathered GEMM: q/k/v = w * (h @ W[e]) ----------------
__global__ __launch_bounds__(256) void expert_qkv_kernel(const float* __restrict__ h,
                                                         const float* __restrict__ qw,
                                                         const float* __restrict__ kw,
                                                         const float* __restrict__ vw,
                                                         const int* __restrict__ counts,
                                                         const int* __restrict__ tok_list,
                                                         const float* __restrict__ wgt_list,
                                                         float* __restrict__ qo,
                                                         float* __restrict__ ko,
                                                         float* __restrict__ vo) {
    int e = blockIdx.x >> 7, chunk = blockIdx.x & 127;
    int cnt = counts[e];
    int base = chunk * 64;
    if (base >= cnt) return;
    int tensor = blockIdx.y;
    const float* W = (tensor == 0 ? qw : tensor == 1 ? kw : vw) + (size_t)e * HIDDEN * HEAD_DIM;
    float* out = tensor == 0 ? qo : tensor == 1 ? ko : vo;

    __shared__ int s_tok[64];
    __shared__ float s_wt[64];
    __shared__ float h_sT[32][68];   // [k][token]
    __shared__ float w_s[32][68];    // [k][d]
    int tid = threadIdx.x;
    if (tid < 64) {
        int idx = base + tid;
        s_tok[tid] = idx < cnt ? tok_list[e * NTOK + idx] : -1;
        s_wt[tid] = idx < cnt ? wgt_list[e * NTOK + idx] : 0.f;
    }
    __syncthreads();
    int tr = tid >> 4, tc = tid & 15;
    float acc[4][4];
    #pragma unroll
    for (int i = 0; i < 4; ++i)
        #pragma unroll
        for (int j = 0; j < 4; ++j) acc[i][j] = 0.f;

    int tokl = tid >> 2, cg = tid & 3;
    int tg_stage = s_tok[tokl];
    int kk = tid >> 3, dg = tid & 7;

    for (int kt = 0; kt < 32; ++kt) {
        __syncthreads();
        #pragma unroll
        for (int r = 0; r < 2; ++r) {
            int c = cg * 8 + r * 4;
            float4 hv = make_float4(0.f, 0.f, 0.f, 0.f);
            if (tg_stage >= 0) hv = *(const float4*)&h[(size_t)tg_stage * HIDDEN + kt * 32 + c];
            h_sT[c + 0][tokl] = hv.x;
            h_sT[c + 1][tokl] = hv.y;
            h_sT[c + 2][tokl] = hv.z;
            h_sT[c + 3][tokl] = hv.w;
        }
        {
            const float* wr = W + (size_t)(kt * 32 + kk) * HEAD_DIM + dg * 8;
            float4 w0 = *(const float4*)wr;
            float4 w1 = *(const float4*)(wr + 4);
            *(float4*)&w_s[kk][dg * 8] = w0;
            *(float4*)&w_s[kk][dg * 8 + 4] = w1;
        }
        __syncthreads();
        #pragma unroll
        for (int k2 = 0; k2 < 32; ++k2) {
            float4 a4 = *(float4*)&h_sT[k2][tr * 4];
            float4 b4 = *(float4*)&w_s[k2][tc * 4];
            float av[4] = {a4.x, a4.y, a4.z, a4.w};
            float bv[4] = {b4.x, b4.y, b4.z, b4.w};
            #pragma unroll
            for (int i = 0; i < 4; ++i)
                #pragma unroll
                for (int j = 0; j < 4; ++j) acc[i][j] += av[i] * bv[j];
        }
    }
    #pragma unroll
    for (int i = 0; i < 4; ++i) {
        int r = tr * 4 + i;
        int tg = s_tok[r];
        if (tg >= 0) {
            float w = s_wt[r];
            #pragma unroll
            for (int j = 0; j < 4; ++j)
                atomicAdd(&out[(size_t)tg * HEAD_DIM + tc * 4 + j], w * acc[i][j]);
        }
    }
}

// ---------------- flash causal attention, fp32 ----------------
__global__ __launch_bounds__(256) void attn_kernel(const float* __restrict__ q,
                                                   const float* __restrict__ k,
                                                   const float* __restrict__ v,
                                                   float* __restrict__ o) {
    int b = blockIdx.y;
    int q0 = blockIdx.x * 32;
    int tid = threadIdx.x;
    int row = tid & 31, grp = tid >> 5;   // 8 groups
    int qg = q0 + row;

    __shared__ float k_s[64][68];
    __shared__ float v_s[64][68];
    __shared__ float p_s[32][68];
    __shared__ float red[8][32];

    float4 qv[16];
    const float* qrow = q + ((size_t)(b * SEQ + qg)) * HEAD_DIM;
    #pragma unroll
    for (int i = 0; i < 16; ++i) qv[i] = *(const float4*)(qrow + i * 4);

    float acc[8];
    #pragma unroll
    for (int i = 0; i < 8; ++i) acc[i] = 0.f;
    float m = -INFINITY, l = 0.f;

    int nkt = (q0 + 32 + 63) >> 6;
    int kr = tid >> 2, dg4 = (tid & 3) * 16;
    int k0 = grp * 8;

    for (int kt = 0; kt < nkt; ++kt) {
        __syncthreads();
        {
            const float* krg = k + ((size_t)(b * SEQ + kt * 64 + kr)) * HEAD_DIM + dg4;
            const float* vrg = v + ((size_t)(b * SEQ + kt * 64 + kr)) * HEAD_DIM + dg4;
            #pragma unroll
            for (int r = 0; r < 4; ++r) {
                *(float4*)&k_s[kr][dg4 + r * 4] = *(const float4*)(krg + r * 4);
                *(float4*)&v_s[kr][dg4 + r * 4] = *(const float4*)(vrg + r * 4);
            }
        }
        __syncthreads();
        float s[8];
        #pragma unroll
        for (int i = 0; i < 8; ++i) s[i] = 0.f;
        #pragma unroll
        for (int d0 = 0; d0 < 16; ++d0) {
            float4 a = qv[d0];
            #pragma unroll
            for (int i = 0; i < 8; ++i) {
                float4 kk4 = *(float4*)&k_s[k0 + i][d0 * 4];
                s[i] += a.x * kk4.x + a.y * kk4.y + a.z * kk4.z + a.w * kk4.w;
            }
        }
        float pm = -INFINITY;
        #pragma unroll
        for (int i = 0; i < 8; ++i) {
            int kg = kt * 64 + k0 + i;
            s[i] = (kg <= qg) ? s[i] * 0.125f : -INFINITY;
            pm = fmaxf(pm, s[i]);
        }
        red[grp][row] = pm;
        __syncthreads();
        float tm = -INFINITY;
        #pragma unroll
        for (int g = 0; g < 8; ++g) tm = fmaxf(tm, red[g][row]);
        float mnew = fmaxf(m, tm);
        float corr = __expf(m - mnew);
        float p[8];
        float psum = 0.f;
        #pragma unroll
        for (int i = 0; i < 8; ++i) {
            p[i] = __expf(s[i] - mnew);
            psum += p[i];
        }
        __syncthreads();
        red[grp][row] = psum;
        __syncthreads();
        float tsum = 0.f;
        #pragma unroll
        for (int g = 0; g < 8; ++g) tsum += red[g][row];
        l = l * corr + tsum;
        m = mnew;
        #pragma unroll
        for (int i = 0; i < 8; ++i) p_s[row][k0 + i] = p[i];
        #pragma unroll
        for (int d = 0; d < 8; ++d) acc[d] *= corr;
        __syncthreads();
        #pragma unroll 8
        for (int k2 = 0; k2 < 64; ++k2) {
            float pv = p_s[row][k2];
            float4 v0 = *(float4*)&v_s[k2][grp * 8];
            float4 v1 = *(float4*)&v_s[k2][grp * 8 + 4];
            acc[0] += pv * v0.x; acc[1] += pv * v0.y; acc[2] += pv * v0.z; acc[3] += pv * v0.w;
            acc[4] += pv * v1.x; acc[5] += pv * v1.y; acc[6] += pv * v1.z; acc[7] += pv * v1.w;
        }
    }
    float invl = 1.f / l;
    float* orow = o + ((size_t)(b * SEQ + qg)) * HEAD_DIM + grp * 8;
    float4 o0 = make_float4(acc[0] * invl, acc[1] * invl, acc[2] * invl, acc[3] * invl);
    float4 o1 = make_float4(acc[4] * invl, acc[5] * invl, acc[6] * invl, acc[7] * invl);
    *(float4*)orow = o0;
    *(float4*)(orow + 4) = o1;
}

// ---------------- token-major output projection, LDS accumulator, NO atomics ----------------
// grid (8192/64, 1024/64) = (128, 16); block 256
__global__ __launch_bounds__(256) void expert_out_v2(const float* __restrict__ attn,
                                                     const float* __restrict__ ow,
                                                     const float* __restrict__ rw_dense,
                                                     float* __restrict__ out) {
    int t0 = blockIdx.x * 64;
    int c0 = blockIdx.y * 64;
    int tid = threadIdx.x;

    __shared__ float x_s[64][68];    // attn rows (unweighted)
    __shared__ float o_s[64][68];    // current expert O panel
    __shared__ float acc_s[64][68];  // output accumulator
    __shared__ float rw_s[64][16];
    __shared__ int lst[64];
    __shared__ int lcnt;

    // stage attn tile: 64 tok x 64 d
    #pragma unroll
    for (int r = 0; r < 4; ++r) {
        int idx = r * 256 + tid;
        int t = idx >> 4, q = idx & 15;
        *(float4*)&x_s[t][q * 4] = *(const float4*)&attn[(size_t)(t0 + t) * HEAD_DIM + q * 4];
        *(float4*)&acc_s[t][q * 4] = make_float4(0.f, 0.f, 0.f, 0.f);
    }
    // stage rw tile: 64 tok x 16
    {
        int t = tid >> 2, eg = tid & 3;
        *(float4*)&rw_s[t][eg * 4] = *(const float4*)&rw_dense[(size_t)(t0 + t) * 16 + eg * 4];
    }
    __syncthreads();

    for (int e = 0; e < 16; ++e) {
        if (tid == 0) lcnt = 0;
        __syncthreads();
        if (tid < 64 && rw_s[tid][e] != 0.f) {
            int p = atomicAdd(&lcnt, 1);
            lst[p] = tid;
        }
        // stage O_e panel: 64 d x 64 cols
        #pragma unroll
        for (int r = 0; r < 4; ++r) {
            int idx = r * 256 + tid;
            int d = idx >> 4, q = idx & 15;
            *(float4*)&o_s[d][q * 4] =
                *(const float4*)&ow[(size_t)e * HEAD_DIM * HIDDEN + (size_t)d * HIDDEN + c0 + q * 4];
        }
        __syncthreads();
        int P = lcnt;
        int pg = tid >> 4, c4 = (tid & 15) * 4;
        for (int p = pg; p < P; p += 16) {
            int t = lst[p];
            float w = rw_s[t][e];
            float sx = 0.f, sy = 0.f, sz = 0.f, sw = 0.f;
            #pragma unroll 8
            for (int d = 0; d < 64; ++d) {
                float xv = x_s[t][d];
                float4 o4 = *(float4*)&o_s[d][c4];
                sx += xv * o4.x; sy += xv * o4.y; sz += xv * o4.z; sw += xv * o4.w;
            }
            float4 a = *(float4*)&acc_s[t][c4];
            a.x += w * sx; a.y += w * sy; a.z += w * sz; a.w += w * sw;
            *(float4*)&acc_s[t][c4] = a;
        }
        __syncthreads();
    }
    // write out, coalesced, no atomics
    #pragma unroll
    for (int r = 0; r < 4; ++r) {
        int idx = r * 256 + tid;
        int t = idx >> 4, q = idx & 15;
        *(float4*)&out[(size_t)(t0 + t) * HIDDEN + c0 + q * 4] = *(float4*)&acc_s[t][q * 4];
    }
}

extern "C" void kernel_launch(void* const* d_in, const int* in_sizes, int n_in,
                              void* d_out, int out_size, void* d_ws, size_t ws_size,
                              hipStream_t stream) {
    const float* h     = (const float*)d_in[0];
    const float* sim   = (const float*)d_in[1];
    const float* gates = (const float*)d_in[2];
    const float* qw    = (const float*)d_in[3];
    const float* kw    = (const float*)d_in[4];
    const float* vw    = (const float*)d_in[5];
    const float* ow    = (const float*)d_in[6];
    float* out = (float*)d_out;

    char* w = (char*)d_ws;
    float* prep     = (float*)(w + OFF_PREP);
    int*   counts   = (int*)(w + OFF_CNT);
    int*   tok_list = (int*)(w + OFF_TOK);
    float* wgt_list = (float*)(w + OFF_WGT);
    float* rw_dense = (float*)(w + OFF_RW);
    float* qb       = (float*)(w + OFF_Q);
    float* kb       = (float*)(w + OFF_K);
    float* vb       = (float*)(w + OFF_V);
    float* attnb    = (float*)(w + OFF_ATTN);

    hipMemsetAsync(counts, 0, 64, stream);
    hipMemsetAsync(qb, 0, 3 * 2097152, stream);           // q,k,v contiguous

    prep_kernel<<<1, 256, 0, stream>>>(sim, gates, prep);
    gating_kernel<<<NTOK, 256, 0, stream>>>(h, sim, prep, counts, tok_list, wgt_list, rw_dense);
    expert_qkv_kernel<<<dim3(16 * 128, 3), 256, 0, stream>>>(h, qw, kw, vw, counts, tok_list,
                                                             wgt_list, qb, kb, vb);
    attn_kernel<<<dim3(64, 4), 256, 0, stream>>>(qb, kb, vb, attnb);
    expert_out_v2<<<dim3(128, 16), 256, 0, stream>>>(attnb, ow, rw_dense, out);
}